// Round 2
// baseline (200.601 us; speedup 1.0000x reference)
//
#include <hip/hip_runtime.h>

// GCN on a directed chain i->i+1 with self-loops.
// Stencil coefficients (from symmetric normalization):
//   deg[0]=1, deg[j>=1]=2  ->  dis[0]=1, dis[j>=1]=1/sqrt(2)
//   out[j] = a_j*h[j] + c_j*h[j-1],  a_0=1, a_j=0.5 (j>=1)
//   c_0=0, c_1=1/sqrt(2), c_j=0.5 (j>=2)
// Layer 3 fuses: stencil(h2@W3)+b3 == (stencil(h2))@W3 + b3  (linearity).
//
// R1 -> R2: gnn_front rewritten with statically-named register arrays
// (no pointer swapping / runtime-indexed arrays -> no scratch spill, rule #20).
// gnn_out: ROWS_PER_BLOCK 64->32 (2048 blocks, 8/CU) + unroll 4 on row loop.

#define N_NODES 8192
#define F_IN 4
#define H1 32
#define H2 16

__device__ __forceinline__ float coefA(int j) { return j == 0 ? 1.0f : 0.5f; }
__device__ __forceinline__ float coefC(int j) {
    return j <= 0 ? 0.0f : (j == 1 ? 0.70710678118654752f : 0.5f);
}

// ---------------- front: x -> g = stencil(h2), [N,16] ----------------
__global__ void __launch_bounds__(256) gnn_front(
    const float* __restrict__ x,  const float* __restrict__ W1, const float* __restrict__ b1,
    const float* __restrict__ W2, const float* __restrict__ b2, float* __restrict__ g)
{
    __shared__ float sW1[F_IN * H1];   // 128
    __shared__ float sW2[H1 * H2];     // 512
    __shared__ float sb1[H1];
    __shared__ float sb2[H2];
    const int t = threadIdx.x;
    if (t < F_IN * H1) sW1[t] = W1[t];
    if (t < H1) sb1[t] = b1[t];
    if (t < H2) sb2[t] = b2[t];
    sW2[t] = W2[t];
    sW2[t + 256] = W2[t + 256];
    __syncthreads();

    const int j = blockIdx.x * blockDim.x + t;

    // t1 row for node jj (zeros if jj < 0); garbage at jj<0 is killed by c=0.
    auto t1row = [&](int jj, float (&o)[H1]) {
        float4 xr = make_float4(0.f, 0.f, 0.f, 0.f);
        if (jj >= 0) xr = *reinterpret_cast<const float4*>(&x[jj * F_IN]);
        #pragma unroll
        for (int k = 0; k < H1; ++k) {
            o[k] = xr.x * sW1[0 * H1 + k] + xr.y * sW1[1 * H1 + k]
                 + xr.z * sW1[2 * H1 + k] + xr.w * sW1[3 * H1 + k];
        }
    };
    // h1[jj] = relu(a*t1[jj] + c*t1[jj-1] + b1)
    auto h1row = [&](int jj, const float (&cur)[H1], const float (&prev)[H1], float (&o)[H1]) {
        const float a = coefA(jj), c = coefC(jj);
        #pragma unroll
        for (int k = 0; k < H1; ++k) {
            float v = a * cur[k] + c * prev[k] + sb1[k];
            o[k] = v > 0.f ? v : 0.f;
        }
    };
    // t2 = h1row @ W2
    auto t2row = [&](const float (&h)[H1], float (&o)[H2]) {
        #pragma unroll
        for (int m = 0; m < H2; ++m) {
            float acc = 0.f;
            #pragma unroll
            for (int k = 0; k < H1; ++k) acc += h[k] * sW2[k * H2 + m];
            o[m] = acc;
        }
    };

    float u[H1], v[H1], h[H1];
    float t2m2[H2], t2m1[H2], t2c[H2];

    // All array names static, all indices compile-time -> VGPRs.
    t1row(j - 3, u);           // u = t1[j-3]
    t1row(j - 2, v);           // v = t1[j-2]
    h1row(j - 2, v, u, h);     // h = h1[j-2]
    t2row(h, t2m2);            // t2[j-2]
    t1row(j - 1, u);           // u = t1[j-1]   (overwrites t1[j-3])
    h1row(j - 1, u, v, h);     // h = h1[j-1]
    t2row(h, t2m1);            // t2[j-1]
    t1row(j, v);               // v = t1[j]     (overwrites t1[j-2])
    h1row(j, v, u, h);         // h = h1[j]
    t2row(h, t2c);             // t2[j]

    const float aj = coefA(j),     cj = coefC(j);
    const float ap = coefA(j - 1), cp = coefC(j - 1);
    float gout[H2];
    #pragma unroll
    for (int m = 0; m < H2; ++m) {
        float h2c = aj * t2c[m]  + cj * t2m1[m] + sb2[m];
        h2c = h2c > 0.f ? h2c : 0.f;
        float h2p = ap * t2m1[m] + cp * t2m2[m] + sb2[m];
        h2p = h2p > 0.f ? h2p : 0.f;
        gout[m] = aj * h2c + cj * h2p;           // g[j] = stencil(h2)[j]
    }
    #pragma unroll
    for (int m = 0; m < H2; m += 4) {
        *reinterpret_cast<float4*>(&g[j * H2 + m]) =
            make_float4(gout[m], gout[m + 1], gout[m + 2], gout[m + 3]);
    }
}

// ---------------- out = g @ W3 + b3, [N, N] ----------------
#define COLS_PER_BLOCK 1024   // 256 threads * float4
#define ROWS_PER_BLOCK 32

__global__ void __launch_bounds__(256) gnn_out(
    const float* __restrict__ g, const float* __restrict__ W3,
    const float* __restrict__ b3, float* __restrict__ out)
{
    __shared__ float gs[ROWS_PER_BLOCK][H2];   // 2 KB
    const int t = threadIdx.x;
    const int col0 = blockIdx.x * COLS_PER_BLOCK + t * 4;
    const int row0 = blockIdx.y * ROWS_PER_BLOCK;

    // stage g rows for this row tile (coalesced)
    #pragma unroll
    for (int i = 0; i < (ROWS_PER_BLOCK * H2) / 256; ++i) {
        const int idx = i * 256 + t;
        reinterpret_cast<float*>(gs)[idx] = g[row0 * H2 + idx];
    }
    __syncthreads();

    // W3 column slab in registers: 16 x float4 = 64 VGPRs, loaded once per block
    float4 w[H2];
    #pragma unroll
    for (int k = 0; k < H2; ++k)
        w[k] = *reinterpret_cast<const float4*>(&W3[k * N_NODES + col0]);
    const float4 bb = *reinterpret_cast<const float4*>(&b3[col0]);

    #pragma unroll 4
    for (int r = 0; r < ROWS_PER_BLOCK; ++r) {
        float4 acc = bb;
        #pragma unroll
        for (int k = 0; k < H2; ++k) {
            const float gv = gs[r][k];   // wave-uniform broadcast (ds_read_b128 x4)
            acc.x += gv * w[k].x;
            acc.y += gv * w[k].y;
            acc.z += gv * w[k].z;
            acc.w += gv * w[k].w;
        }
        *reinterpret_cast<float4*>(&out[(size_t)(row0 + r) * N_NODES + col0]) = acc;
    }
}

extern "C" void kernel_launch(void* const* d_in, const int* in_sizes, int n_in,
                              void* d_out, int out_size, void* d_ws, size_t ws_size,
                              hipStream_t stream) {
    const float* x  = (const float*)d_in[0];
    const float* W1 = (const float*)d_in[1];
    const float* b1 = (const float*)d_in[2];
    const float* W2 = (const float*)d_in[3];
    const float* b2 = (const float*)d_in[4];
    const float* W3 = (const float*)d_in[5];
    const float* b3 = (const float*)d_in[6];
    // d_in[7] = edge_index: fixed directed chain i->i+1 (structure hardcoded above)

    float* g   = (float*)d_ws;            // [N_NODES, H2] = 512 KB
    float* out = (float*)d_out;

    gnn_front<<<N_NODES / 256, 256, 0, stream>>>(x, W1, b1, W2, b2, g);

    dim3 grid(N_NODES / COLS_PER_BLOCK, N_NODES / ROWS_PER_BLOCK);  // 8 x 256
    gnn_out<<<grid, 256, 0, stream>>>(g, W3, b3, out);
}

// Round 3
// 103.854 us; speedup vs baseline: 1.9316x; 1.9316x over previous
//
#include <hip/hip_runtime.h>

// GCN on a directed chain i->i+1 with self-loops.
// Stencil coefficients (symmetric normalization):
//   deg[0]=1, deg[j>=1]=2  ->  dis[0]=1, dis[j>=1]=1/sqrt(2)
//   out[j] = a_j*h[j] + c_j*h[j-1],  a_0=1, a_j=0.5 (j>=1)
//   c_0=0, c_1=1/sqrt(2), c_j=0.5 (j>=2)
// Layer 3 fuses: stencil(h2@W3)+b3 == (stencil(h2))@W3 + b3  (linearity).
//
// R2 -> R3: front split into two small kernels (gnn_t2, gnn_g) so per-thread
// live state stays ~40-60 VGPRs (R2's monolith spilled: VGPR=256, FETCH=15MB
// of scratch traffic, 166us). t1 rows recomputed per-thread (2x redundant,
// trivially cheap) instead of carried across a register pipeline.

#define N_NODES 8192
#define F_IN 4
#define H1 32
#define H2 16

__device__ __forceinline__ float coefA(int j) { return j == 0 ? 1.0f : 0.5f; }
__device__ __forceinline__ float coefC(int j) {
    return j <= 0 ? 0.0f : (j == 1 ? 0.70710678118654752f : 0.5f);
}

// ---------- stage 1: t2[j] = relu(stencil(x@W1)+b1) @ W2, [N,16] ----------
__global__ void __launch_bounds__(64) gnn_t2(
    const float* __restrict__ x,  const float* __restrict__ W1,
    const float* __restrict__ b1, const float* __restrict__ W2,
    float* __restrict__ t2)
{
    __shared__ float sW1t[H1 * F_IN];  // transposed: [k][f], one b128 per k
    __shared__ float sb1[H1];
    __shared__ float sW2[H1 * H2];     // row-major [k][m]
    const int t = threadIdx.x;
    #pragma unroll
    for (int i = 0; i < 2; ++i) {
        const int idx = i * 64 + t;                  // 0..127
        sW1t[idx] = W1[(idx & 3) * H1 + (idx >> 2)]; // sW1t[k*4+f] = W1[f][k]
    }
    if (t < H1) sb1[t] = b1[t];
    #pragma unroll
    for (int i = 0; i < 8; ++i) sW2[i * 64 + t] = W2[i * 64 + t];
    __syncthreads();

    const int j = blockIdx.x * 64 + t;
    const float4 xc = *reinterpret_cast<const float4*>(&x[j * F_IN]);
    float4 xp = make_float4(0.f, 0.f, 0.f, 0.f);
    if (j >= 1) xp = *reinterpret_cast<const float4*>(&x[(j - 1) * F_IN]);
    const float aj = coefA(j), cj = coefC(j);

    float acc[H2];
    #pragma unroll
    for (int m = 0; m < H2; ++m) acc[m] = 0.f;

    #pragma unroll
    for (int k = 0; k < H1; ++k) {
        const float4 w = *reinterpret_cast<const float4*>(&sW1t[k * 4]);
        const float t1c = xc.x * w.x + xc.y * w.y + xc.z * w.z + xc.w * w.w;
        const float t1p = xp.x * w.x + xp.y * w.y + xp.z * w.z + xp.w * w.w;
        float h = aj * t1c + cj * t1p + sb1[k];
        h = h > 0.f ? h : 0.f;
        #pragma unroll
        for (int m = 0; m < H2; ++m) acc[m] += h * sW2[k * H2 + m];
    }
    #pragma unroll
    for (int m = 0; m < H2; m += 4) {
        *reinterpret_cast<float4*>(&t2[j * H2 + m]) =
            make_float4(acc[m], acc[m + 1], acc[m + 2], acc[m + 3]);
    }
}

// ---------- stage 2: g[j] = stencil(relu(stencil(t2)+b2))[j], [N,16] ----------
__global__ void __launch_bounds__(64) gnn_g(
    const float* __restrict__ t2, const float* __restrict__ b2,
    float* __restrict__ g)
{
    const int j = blockIdx.x * 64 + threadIdx.x;

    float m2[H2], m1[H2], c0[H2];
    #pragma unroll
    for (int m = 0; m < H2; ++m) { m2[m] = 0.f; m1[m] = 0.f; }
    #pragma unroll
    for (int m = 0; m < H2; m += 4) {
        const float4 v = *reinterpret_cast<const float4*>(&t2[j * H2 + m]);
        c0[m] = v.x; c0[m + 1] = v.y; c0[m + 2] = v.z; c0[m + 3] = v.w;
        if (j >= 1) {
            const float4 p = *reinterpret_cast<const float4*>(&t2[(j - 1) * H2 + m]);
            m1[m] = p.x; m1[m + 1] = p.y; m1[m + 2] = p.z; m1[m + 3] = p.w;
        }
        if (j >= 2) {
            const float4 q = *reinterpret_cast<const float4*>(&t2[(j - 2) * H2 + m]);
            m2[m] = q.x; m2[m + 1] = q.y; m2[m + 2] = q.z; m2[m + 3] = q.w;
        }
    }

    const float aj = coefA(j),     cj = coefC(j);
    const float ap = coefA(j - 1), cp = coefC(j - 1);
    float gout[H2];
    #pragma unroll
    for (int m = 0; m < H2; ++m) {
        const float bm = b2[m];
        float h2c = aj * c0[m] + cj * m1[m] + bm;
        h2c = h2c > 0.f ? h2c : 0.f;
        float h2p = ap * m1[m] + cp * m2[m] + bm;
        h2p = h2p > 0.f ? h2p : 0.f;
        gout[m] = aj * h2c + cj * h2p;     // g[j] = stencil(h2)[j]
    }
    #pragma unroll
    for (int m = 0; m < H2; m += 4) {
        *reinterpret_cast<float4*>(&g[j * H2 + m]) =
            make_float4(gout[m], gout[m + 1], gout[m + 2], gout[m + 3]);
    }
}

// ---------------- out = g @ W3 + b3, [N, N] ----------------
#define COLS_PER_BLOCK 1024   // 256 threads * float4
#define ROWS_PER_BLOCK 32

__global__ void __launch_bounds__(256) gnn_out(
    const float* __restrict__ g, const float* __restrict__ W3,
    const float* __restrict__ b3, float* __restrict__ out)
{
    __shared__ float gs[ROWS_PER_BLOCK][H2];   // 2 KB
    const int t = threadIdx.x;
    const int col0 = blockIdx.x * COLS_PER_BLOCK + t * 4;
    const int row0 = blockIdx.y * ROWS_PER_BLOCK;

    // stage g rows for this row tile (coalesced)
    #pragma unroll
    for (int i = 0; i < (ROWS_PER_BLOCK * H2) / 256; ++i) {
        const int idx = i * 256 + t;
        reinterpret_cast<float*>(gs)[idx] = g[row0 * H2 + idx];
    }
    __syncthreads();

    // W3 column slab in registers: 16 x float4 = 64 VGPRs, loaded once per block
    float4 w[H2];
    #pragma unroll
    for (int k = 0; k < H2; ++k)
        w[k] = *reinterpret_cast<const float4*>(&W3[k * N_NODES + col0]);
    const float4 bb = *reinterpret_cast<const float4*>(&b3[col0]);

    #pragma unroll 4
    for (int r = 0; r < ROWS_PER_BLOCK; ++r) {
        float4 acc = bb;
        #pragma unroll
        for (int k = 0; k < H2; ++k) {
            const float gv = gs[r][k];   // wave-uniform broadcast
            acc.x += gv * w[k].x;
            acc.y += gv * w[k].y;
            acc.z += gv * w[k].z;
            acc.w += gv * w[k].w;
        }
        *reinterpret_cast<float4*>(&out[(size_t)(row0 + r) * N_NODES + col0]) = acc;
    }
}

extern "C" void kernel_launch(void* const* d_in, const int* in_sizes, int n_in,
                              void* d_out, int out_size, void* d_ws, size_t ws_size,
                              hipStream_t stream) {
    const float* x  = (const float*)d_in[0];
    const float* W1 = (const float*)d_in[1];
    const float* b1 = (const float*)d_in[2];
    const float* W2 = (const float*)d_in[3];
    const float* b2 = (const float*)d_in[4];
    const float* W3 = (const float*)d_in[5];
    const float* b3 = (const float*)d_in[6];
    // d_in[7] = edge_index: fixed directed chain i->i+1 (structure hardcoded above)

    float* t2  = (float*)d_ws;                       // [N,16] = 512 KB
    float* g   = (float*)d_ws + N_NODES * H2;        // [N,16] = 512 KB
    float* out = (float*)d_out;

    gnn_t2<<<N_NODES / 64, 64, 0, stream>>>(x, W1, b1, W2, t2);
    gnn_g <<<N_NODES / 64, 64, 0, stream>>>(t2, b2, g);

    dim3 grid(N_NODES / COLS_PER_BLOCK, N_NODES / ROWS_PER_BLOCK);  // 8 x 256
    gnn_out<<<grid, 256, 0, stream>>>(g, W3, b3, out);
}